// Round 1
// baseline (327.924 us; speedup 1.0000x reference)
//
#include <hip/hip_runtime.h>
#include <hip/hip_bf16.h>
#include <math.h>

// MoE: B=2,S=1024,D=1024,E=8,H=3584, top-1 routing.
// Pipeline: router -> aux(losses+offsets) -> scatter(token lists) ->
//           gemm(x@W1^T)->g1, gemm(x@W2^T)->g2 -> swiglu -> gemm(h@W3^T)->out.
// All GEMMs: bf16 MFMA 16x16x32, f32 accumulate, 128x128x64 tiles.

#define NB 2
#define NS 1024
#define ND 1024
#define NE 8
#define NH 3584
#define NTOK 2048

typedef float f32x4 __attribute__((ext_vector_type(4)));
typedef __bf16 bf16x8 __attribute__((ext_vector_type(8)));
typedef unsigned short u16x4 __attribute__((ext_vector_type(4)));
typedef unsigned int u32x4 __attribute__((ext_vector_type(4)));

__device__ __forceinline__ unsigned short f2bf(float f) {
  unsigned int u = __builtin_bit_cast(unsigned int, f);
  u = (u + 0x7fffu + ((u >> 16) & 1u)) >> 16;   // RNE
  return (unsigned short)u;
}
__device__ __forceinline__ float bf2f(unsigned short s) {
  unsigned int u = ((unsigned int)s) << 16;
  return __builtin_bit_cast(float, u);
}

// ---------------- router: logits, softmax, top-1, lse ----------------
__global__ __launch_bounds__(256) void router_kernel(
    const float* __restrict__ x, const float* __restrict__ Wr,
    float* __restrict__ probs, float* __restrict__ lse,
    int* __restrict__ counts, int* __restrict__ expert_of)
{
  int n = blockIdx.x;
  int t = threadIdx.x;
  const float* xr = x + (size_t)n * ND;
  float xv[4];
#pragma unroll
  for (int j = 0; j < 4; ++j) xv[j] = xr[t + j * 256];
  float p[NE];
#pragma unroll
  for (int e = 0; e < NE; ++e) p[e] = 0.f;
#pragma unroll
  for (int j = 0; j < 4; ++j) {
    int d = t + j * 256;
#pragma unroll
    for (int e = 0; e < NE; ++e) p[e] += xv[j] * Wr[e * ND + d];
  }
#pragma unroll
  for (int e = 0; e < NE; ++e) {
#pragma unroll
    for (int o = 32; o > 0; o >>= 1) p[e] += __shfl_down(p[e], o, 64);
  }
  __shared__ float red[4][NE];
  int wid = t >> 6, lane = t & 63;
  if (lane == 0) {
#pragma unroll
    for (int e = 0; e < NE; ++e) red[wid][e] = p[e];
  }
  __syncthreads();
  if (t == 0) {
    float lg[NE];
#pragma unroll
    for (int e = 0; e < NE; ++e) lg[e] = red[0][e] + red[1][e] + red[2][e] + red[3][e];
    float m = lg[0]; int arg = 0;
#pragma unroll
    for (int e = 1; e < NE; ++e) if (lg[e] > m) { m = lg[e]; arg = e; }
    float s = 0.f, ex[NE];
#pragma unroll
    for (int e = 0; e < NE; ++e) { ex[e] = expf(lg[e] - m); s += ex[e]; }
    float inv = 1.f / s;
#pragma unroll
    for (int e = 0; e < NE; ++e) probs[n * NE + e] = ex[e] * inv;
    lse[n] = m + logf(s);
    expert_of[n] = arg;
    atomicAdd(&counts[arg], 1);
  }
}

// ---------------- aux losses + prefix offsets ----------------
__global__ __launch_bounds__(256) void aux_offsets_kernel(
    const float* __restrict__ probs, const float* __restrict__ lse,
    const int* __restrict__ counts, int* __restrict__ offsets,
    int* __restrict__ cursors, float* __restrict__ out_aux)
{
  int t = threadIdx.x;
  float lsum = 0.f;
  for (int n = t; n < NTOK; n += 256) lsum += lse[n];
  float esum = 0.f, esq = 0.f;
  for (int i = t; i < NS * NE; i += 256) {
    float v = probs[i] + probs[NS * NE + i];  // sum over batch dim (B=2)
    esum += v; esq += v * v;
  }
  __shared__ float rb[3][4];
  int wid = t >> 6, lane = t & 63;
#pragma unroll
  for (int o = 32; o > 0; o >>= 1) {
    lsum += __shfl_down(lsum, o, 64);
    esum += __shfl_down(esum, o, 64);
    esq  += __shfl_down(esq, o, 64);
  }
  if (lane == 0) { rb[0][wid] = lsum; rb[1][wid] = esum; rb[2][wid] = esq; }
  __syncthreads();
  if (t == 0) {
    lsum = rb[0][0] + rb[0][1] + rb[0][2] + rb[0][3];
    esum = rb[1][0] + rb[1][1] + rb[1][2] + rb[1][3];
    esq  = rb[2][0] + rb[2][1] + rb[2][2] + rb[2][3];
    float zmean = lsum / (float)NTOK;
    float z_loss = zmean * zmean;
    const float nn = (float)(NS * NE);
    float mean = esum / nn;
    float var = (esq - esum * esum / nn) / (nn - 1.0f);   // ddof=1
    float load_loss = var / (mean * mean);
    out_aux[0] = 1e-3f * z_loss + 1e-3f * load_loss;
    int off = 0;
#pragma unroll
    for (int e = 0; e < NE; ++e) { offsets[e] = off; cursors[e] = off; off += counts[e]; }
    offsets[NE] = off;
  }
}

// ---------------- build per-expert token lists ----------------
__global__ __launch_bounds__(256) void scatter_kernel(
    const int* __restrict__ expert_of, int* __restrict__ cursors,
    int* __restrict__ token_list)
{
  int n = blockIdx.x * 256 + threadIdx.x;
  int e = expert_of[n];
  int p = atomicAdd(&cursors[e], 1);
  token_list[p] = n;
}

// ---------------- grouped BT-GEMM: C[m,n] = sum_k A[m,k] * W[e][n,k] ----------------
#define BM 128
#define BN 128
#define BK 64
#define LDK 72   // +8 bf16 pad -> 144B row stride, kills 128B-stride bank conflict

template<int KDIM, bool GATHER_A, bool SCATTER_OUT>
__global__ __launch_bounds__(256) void moe_gemm(
    const float* __restrict__ Af32,          // GATHER_A: x [NTOK][KDIM] f32, gathered via token_list
    const unsigned short* __restrict__ Abf,  // !GATHER_A: h [NTOK][KDIM] bf16, list order
    const float* __restrict__ Wbase,         // [E][n_out][KDIM] f32
    const int* __restrict__ offsets,
    const int* __restrict__ token_list,
    unsigned short* __restrict__ Cbf,        // !SCATTER_OUT: [NTOK][n_out] bf16, list order
    float* __restrict__ Cf32,                // SCATTER_OUT: d_out [NTOK][n_out] f32, by token
    int n_out)
{
  int e = blockIdx.z;
  int base = offsets[e];
  int cnt = offsets[e + 1] - base;
  int m0 = blockIdx.y * BM;
  if (m0 >= cnt) return;
  int n0 = blockIdx.x * BN;
  const float* W = Wbase + (size_t)e * ((size_t)n_out * KDIM);

  __shared__ __align__(16) unsigned short As[BM][LDK];
  __shared__ __align__(16) unsigned short Bs[BN][LDK];
  __shared__ int rowtok[BM];

  int t = threadIdx.x;
  if (t < BM) {
    int mc = m0 + t; if (mc > cnt - 1) mc = cnt - 1;
    rowtok[t] = token_list[base + mc];       // token id (gather A / scatter C)
  }
  __syncthreads();

  int lane = t & 63;
  int wid = t >> 6;
  int wm = (wid >> 1) * 64;
  int wn = (wid & 1) * 64;

  f32x4 acc[4][4] = {};

  const int nsteps = KDIM / BK;
  for (int ks = 0; ks < nsteps; ++ks) {
    int k0 = ks * BK;
    {
      int rsub = t >> 4;            // 0..15
      int c4 = (t & 15) * 4;        // f32 col
      // weights tile (always f32 -> bf16)
#pragma unroll
      for (int rr = 0; rr < 8; ++rr) {
        int row = rr * 16 + rsub;
        f32x4 wv = *(const f32x4*)(W + (size_t)(n0 + row) * KDIM + k0 + c4);
        u16x4 wp;
        wp[0] = f2bf(wv[0]); wp[1] = f2bf(wv[1]); wp[2] = f2bf(wv[2]); wp[3] = f2bf(wv[3]);
        *(u16x4*)&As[0][0 == 0 ? 0 : 0], *(u16x4*)&Bs[row][c4] = wp;
      }
      if (GATHER_A) {
#pragma unroll
        for (int rr = 0; rr < 8; ++rr) {
          int row = rr * 16 + rsub;
          const float* src = Af32 + (size_t)rowtok[row] * KDIM + k0 + c4;
          f32x4 av = *(const f32x4*)src;
          u16x4 ap;
          ap[0] = f2bf(av[0]); ap[1] = f2bf(av[1]); ap[2] = f2bf(av[2]); ap[3] = f2bf(av[3]);
          *(u16x4*)&As[row][c4] = ap;
        }
      } else {
        int rsub8 = t >> 3;         // 0..31
        int c8 = (t & 7) * 8;       // bf16 col
#pragma unroll
        for (int rr = 0; rr < 4; ++rr) {
          int row = rr * 32 + rsub8;
          int mc = m0 + row; if (mc > cnt - 1) mc = cnt - 1;
          u32x4 v = *(const u32x4*)(Abf + (size_t)(base + mc) * KDIM + k0 + c8);
          *(u32x4*)&As[row][c8] = v;
        }
      }
    }
    __syncthreads();
#pragma unroll
    for (int kk = 0; kk < 2; ++kk) {
      int klo = kk * 32 + (lane >> 4) * 8;
      int rl = lane & 15;
      bf16x8 af[4], bv[4];
#pragma unroll
      for (int i = 0; i < 4; ++i) af[i] = *(const bf16x8*)&As[wm + i * 16 + rl][klo];
#pragma unroll
      for (int j = 0; j < 4; ++j) bv[j] = *(const bf16x8*)&Bs[wn + j * 16 + rl][klo];
#pragma unroll
      for (int i = 0; i < 4; ++i)
#pragma unroll
        for (int j = 0; j < 4; ++j)
          acc[i][j] = __builtin_amdgcn_mfma_f32_16x16x32_bf16(af[i], bv[j], acc[i][j], 0, 0, 0);
    }
    __syncthreads();
  }

  int rl = lane & 15;
  int rq = lane >> 4;
#pragma unroll
  for (int i = 0; i < 4; ++i) {
#pragma unroll
    for (int r = 0; r < 4; ++r) {
      int mrow = wm + i * 16 + rq * 4 + r;
      int m = m0 + mrow;
      if (m < cnt) {
#pragma unroll
        for (int j = 0; j < 4; ++j) {
          int ncol = n0 + wn + j * 16 + rl;
          float v = acc[i][j][r];
          if (SCATTER_OUT) {
            Cf32[(size_t)rowtok[mrow] * n_out + ncol] = v;
          } else {
            Cbf[(size_t)(base + m) * n_out + ncol] = f2bf(v);
          }
        }
      }
    }
  }
}

// ---------------- SwiGLU: h = silu(g1) * g2 ----------------
__global__ __launch_bounds__(256) void swiglu_kernel(
    const unsigned short* __restrict__ g1, const unsigned short* __restrict__ g2,
    unsigned short* __restrict__ h)
{
  size_t i = ((size_t)blockIdx.x * 256 + threadIdx.x) * 8;
  u32x4 a = *(const u32x4*)(g1 + i);
  u32x4 b = *(const u32x4*)(g2 + i);
  u32x4 o;
#pragma unroll
  for (int j = 0; j < 4; ++j) {
    float a0 = bf2f((unsigned short)(a[j] & 0xffffu));
    float a1 = bf2f((unsigned short)(a[j] >> 16));
    float b0 = bf2f((unsigned short)(b[j] & 0xffffu));
    float b1 = bf2f((unsigned short)(b[j] >> 16));
    float s0 = a0 / (1.f + expf(-a0)) * b0;
    float s1 = a1 / (1.f + expf(-a1)) * b1;
    o[j] = (unsigned int)f2bf(s0) | ((unsigned int)f2bf(s1) << 16);
  }
  *(u32x4*)(h + i) = o;
}

extern "C" void kernel_launch(void* const* d_in, const int* in_sizes, int n_in,
                              void* d_out, int out_size, void* d_ws, size_t ws_size,
                              hipStream_t stream)
{
  (void)in_sizes; (void)n_in; (void)out_size; (void)ws_size;
  const float* x  = (const float*)d_in[0];
  const float* Wr = (const float*)d_in[1];
  const float* W1 = (const float*)d_in[2];
  const float* W2 = (const float*)d_in[3];
  const float* W3 = (const float*)d_in[4];
  float* out = (float*)d_out;

  char* w = (char*)d_ws;
  float* probs    = (float*)(w + 0);        // 65536 B
  float* lse      = (float*)(w + 65536);    // 8192 B
  int* counts     = (int*)(w + 73728);      // 32 B
  int* cursors    = (int*)(w + 73760);      // 32 B
  int* offsets    = (int*)(w + 73792);      // 64 B
  int* expert_of  = (int*)(w + 73856);      // 8192 B
  int* token_list = (int*)(w + 82048);      // 8192 B
  unsigned short* g1 = (unsigned short*)(w + 131072);   // 14680064 B each
  unsigned short* g2 = g1 + (size_t)NTOK * NH;
  unsigned short* h  = g2 + (size_t)NTOK * NH;

  hipMemsetAsync(counts, 0, 32, stream);
  router_kernel<<<NTOK, 256, 0, stream>>>(x, Wr, probs, lse, counts, expert_of);
  aux_offsets_kernel<<<1, 256, 0, stream>>>(probs, lse, counts, offsets, cursors,
                                            out + (size_t)NTOK * ND);
  scatter_kernel<<<NTOK / 256, 256, 0, stream>>>(expert_of, cursors, token_list);
  moe_gemm<ND, true, false><<<dim3(NH / BN, NTOK / BM, NE), 256, 0, stream>>>(
      x, nullptr, W1, offsets, token_list, g1, nullptr, NH);
  moe_gemm<ND, true, false><<<dim3(NH / BN, NTOK / BM, NE), 256, 0, stream>>>(
      x, nullptr, W2, offsets, token_list, g2, nullptr, NH);
  swiglu_kernel<<<(NTOK * NH) / (256 * 8), 256, 0, stream>>>(g1, g2, h);
  moe_gemm<NH, false, true><<<dim3(ND / BN, NTOK / BM, NE), 256, 0, stream>>>(
      nullptr, h, W3, offsets, token_list, nullptr, out, ND);
}

// Round 2
// 243.470 us; speedup vs baseline: 1.3469x; 1.3469x over previous
//
#include <hip/hip_runtime.h>
#include <hip/hip_bf16.h>
#include <math.h>

// MoE: B=2,S=1024,D=1024,E=8,H=3584, top-1 routing.
// router -> aux -> scatter -> gemm12 (x@W1^T, x@W2^T fused + SwiGLU -> h bf16)
//                          -> gemm3  (h@W3^T -> out f32, token scatter)
// GEMMs: bf16 MFMA 16x16x32, f32 acc, double-buffered LDS, reg-staged async pipeline.

#define NB 2
#define NS 1024
#define ND 1024
#define NE 8
#define NH 3584
#define NTOK 2048
#define LDK 72   // +8 bf16 pad -> 144B row stride (conflict-free for b128 reads)

typedef float f32x4 __attribute__((ext_vector_type(4)));
typedef __bf16 bf16x8 __attribute__((ext_vector_type(8)));
typedef unsigned short u16x4 __attribute__((ext_vector_type(4)));
typedef unsigned int u32x4 __attribute__((ext_vector_type(4)));

__device__ __forceinline__ unsigned short f2bf(float f) {
  unsigned int u = __builtin_bit_cast(unsigned int, f);
  u = (u + 0x7fffu + ((u >> 16) & 1u)) >> 16;   // RNE
  return (unsigned short)u;
}
__device__ __forceinline__ float bf2f(unsigned short s) {
  unsigned int u = ((unsigned int)s) << 16;
  return __builtin_bit_cast(float, u);
}

// ---------------- router: logits, softmax, top-1, lse ----------------
__global__ __launch_bounds__(256) void router_kernel(
    const float* __restrict__ x, const float* __restrict__ Wr,
    float* __restrict__ probs, float* __restrict__ lse,
    int* __restrict__ counts, int* __restrict__ expert_of)
{
  int n = blockIdx.x;
  int t = threadIdx.x;
  const float* xr = x + (size_t)n * ND;
  float xv[4];
#pragma unroll
  for (int j = 0; j < 4; ++j) xv[j] = xr[t + j * 256];
  float p[NE];
#pragma unroll
  for (int e = 0; e < NE; ++e) p[e] = 0.f;
#pragma unroll
  for (int j = 0; j < 4; ++j) {
    int d = t + j * 256;
#pragma unroll
    for (int e = 0; e < NE; ++e) p[e] += xv[j] * Wr[e * ND + d];
  }
#pragma unroll
  for (int e = 0; e < NE; ++e) {
#pragma unroll
    for (int o = 32; o > 0; o >>= 1) p[e] += __shfl_down(p[e], o, 64);
  }
  __shared__ float red[4][NE];
  int wid = t >> 6, lane = t & 63;
  if (lane == 0) {
#pragma unroll
    for (int e = 0; e < NE; ++e) red[wid][e] = p[e];
  }
  __syncthreads();
  if (t == 0) {
    float lg[NE];
#pragma unroll
    for (int e = 0; e < NE; ++e) lg[e] = red[0][e] + red[1][e] + red[2][e] + red[3][e];
    float m = lg[0]; int arg = 0;
#pragma unroll
    for (int e = 1; e < NE; ++e) if (lg[e] > m) { m = lg[e]; arg = e; }
    float s = 0.f, ex[NE];
#pragma unroll
    for (int e = 0; e < NE; ++e) { ex[e] = expf(lg[e] - m); s += ex[e]; }
    float inv = 1.f / s;
#pragma unroll
    for (int e = 0; e < NE; ++e) probs[n * NE + e] = ex[e] * inv;
    lse[n] = m + logf(s);
    expert_of[n] = arg;
    atomicAdd(&counts[arg], 1);
  }
}

// ---------------- aux losses + prefix offsets ----------------
__global__ __launch_bounds__(256) void aux_offsets_kernel(
    const float* __restrict__ probs, const float* __restrict__ lse,
    const int* __restrict__ counts, int* __restrict__ offsets,
    int* __restrict__ cursors, float* __restrict__ out_aux)
{
  int t = threadIdx.x;
  float lsum = 0.f;
  for (int n = t; n < NTOK; n += 256) lsum += lse[n];
  float esum = 0.f, esq = 0.f;
  for (int i = t; i < NS * NE; i += 256) {
    float v = probs[i] + probs[NS * NE + i];  // sum over batch dim (B=2)
    esum += v; esq += v * v;
  }
  __shared__ float rb[3][4];
  int wid = t >> 6, lane = t & 63;
#pragma unroll
  for (int o = 32; o > 0; o >>= 1) {
    lsum += __shfl_down(lsum, o, 64);
    esum += __shfl_down(esum, o, 64);
    esq  += __shfl_down(esq, o, 64);
  }
  if (lane == 0) { rb[0][wid] = lsum; rb[1][wid] = esum; rb[2][wid] = esq; }
  __syncthreads();
  if (t == 0) {
    lsum = rb[0][0] + rb[0][1] + rb[0][2] + rb[0][3];
    esum = rb[1][0] + rb[1][1] + rb[1][2] + rb[1][3];
    esq  = rb[2][0] + rb[2][1] + rb[2][2] + rb[2][3];
    float zmean = lsum / (float)NTOK;
    float z_loss = zmean * zmean;
    const float nn = (float)(NS * NE);
    float mean = esum / nn;
    float var = (esq - esum * esum / nn) / (nn - 1.0f);   // ddof=1
    float load_loss = var / (mean * mean);
    out_aux[0] = 1e-3f * z_loss + 1e-3f * load_loss;
    int off = 0;
#pragma unroll
    for (int e = 0; e < NE; ++e) { offsets[e] = off; cursors[e] = off; off += counts[e]; }
    offsets[NE] = off;
  }
}

// ---------------- build per-expert token lists ----------------
__global__ __launch_bounds__(256) void scatter_kernel(
    const int* __restrict__ expert_of, int* __restrict__ cursors,
    int* __restrict__ token_list)
{
  int n = blockIdx.x * 256 + threadIdx.x;
  int e = expert_of[n];
  int p = atomicAdd(&cursors[e], 1);
  token_list[p] = n;
}

// ---------------- fused GEMM12: g1=x@W1^T, g2=x@W2^T, h=silu(g1)*g2 ----------------
// BM=128 tokens x BN=64 h-cols per block; BK=64; 4 waves in 2x2; double-buffered LDS;
// per step: issue next-step global loads -> MFMA current -> convert+ds_write next -> barrier.
__global__ __launch_bounds__(256, 2) void moe_gemm12(
    const float* __restrict__ x, const float* __restrict__ W1f,
    const float* __restrict__ W2f, const int* __restrict__ offsets,
    const int* __restrict__ token_list, unsigned short* __restrict__ h)
{
  int e = blockIdx.z;
  int base = offsets[e], cnt = offsets[e + 1] - base;
  int m0 = blockIdx.y * 128;
  if (m0 >= cnt) return;
  int n0 = blockIdx.x * 64;
  const float* B1 = W1f + (size_t)e * ((size_t)NH * ND) + (size_t)n0 * ND;
  const float* B2 = W2f + (size_t)e * ((size_t)NH * ND) + (size_t)n0 * ND;

  __shared__ __align__(16) unsigned short As[2][128][LDK];
  __shared__ __align__(16) unsigned short B1s[2][64][LDK];
  __shared__ __align__(16) unsigned short B2s[2][64][LDK];
  __shared__ int rowtok[128];

  int t = threadIdx.x;
  if (t < 128) {
    int mc = m0 + t; if (mc > cnt - 1) mc = cnt - 1;
    rowtok[t] = token_list[base + mc];
  }
  __syncthreads();

  int rsub = t >> 4;            // 0..15
  int c4 = (t & 15) * 4;        // f32 col within BK

  const float* asrc[8];
#pragma unroll
  for (int rr = 0; rr < 8; ++rr)
    asrc[rr] = x + (size_t)rowtok[rr * 16 + rsub] * ND + c4;
  const float* b1src = B1 + (size_t)rsub * ND + c4;
  const float* b2src = B2 + (size_t)rsub * ND + c4;

  f32x4 ra[8], rb1[4], rb2[4];

  auto load_step = [&](int k0) {
#pragma unroll
    for (int rr = 0; rr < 8; ++rr) ra[rr] = *(const f32x4*)(asrc[rr] + k0);
#pragma unroll
    for (int rr = 0; rr < 4; ++rr) {
      rb1[rr] = *(const f32x4*)(b1src + (size_t)rr * 16 * ND + k0);
      rb2[rr] = *(const f32x4*)(b2src + (size_t)rr * 16 * ND + k0);
    }
  };
  auto store_buf = [&](int buf) {
#pragma unroll
    for (int rr = 0; rr < 8; ++rr) {
      u16x4 p;
      p[0] = f2bf(ra[rr][0]); p[1] = f2bf(ra[rr][1]);
      p[2] = f2bf(ra[rr][2]); p[3] = f2bf(ra[rr][3]);
      *(u16x4*)&As[buf][rr * 16 + rsub][c4] = p;
    }
#pragma unroll
    for (int rr = 0; rr < 4; ++rr) {
      u16x4 p, q;
      p[0] = f2bf(rb1[rr][0]); p[1] = f2bf(rb1[rr][1]);
      p[2] = f2bf(rb1[rr][2]); p[3] = f2bf(rb1[rr][3]);
      q[0] = f2bf(rb2[rr][0]); q[1] = f2bf(rb2[rr][1]);
      q[2] = f2bf(rb2[rr][2]); q[3] = f2bf(rb2[rr][3]);
      *(u16x4*)&B1s[buf][rr * 16 + rsub][c4] = p;
      *(u16x4*)&B2s[buf][rr * 16 + rsub][c4] = q;
    }
  };

  int lane = t & 63, wid = t >> 6;
  int wm = (wid >> 1) * 64;   // 0 / 64
  int wn = (wid & 1) * 32;    // 0 / 32
  int rl = lane & 15;
  int ksel = (lane >> 4) * 8;

  f32x4 acc1[4][2] = {}, acc2[4][2] = {};

  load_step(0);
  store_buf(0);
  __syncthreads();

  const int NSTEP = ND / 64;   // 16
  for (int ks = 0; ks < NSTEP; ++ks) {
    int cur = ks & 1;
    bool more = (ks + 1) < NSTEP;
    if (more) load_step((ks + 1) * 64);
#pragma unroll
    for (int kk = 0; kk < 2; ++kk) {
      int klo = kk * 32 + ksel;
      bf16x8 af[4], b1[2], b2[2];
#pragma unroll
      for (int i = 0; i < 4; ++i) af[i] = *(const bf16x8*)&As[cur][wm + i * 16 + rl][klo];
#pragma unroll
      for (int j = 0; j < 2; ++j) {
        b1[j] = *(const bf16x8*)&B1s[cur][wn + j * 16 + rl][klo];
        b2[j] = *(const bf16x8*)&B2s[cur][wn + j * 16 + rl][klo];
      }
#pragma unroll
      for (int i = 0; i < 4; ++i)
#pragma unroll
        for (int j = 0; j < 2; ++j) {
          acc1[i][j] = __builtin_amdgcn_mfma_f32_16x16x32_bf16(af[i], b1[j], acc1[i][j], 0, 0, 0);
          acc2[i][j] = __builtin_amdgcn_mfma_f32_16x16x32_bf16(af[i], b2[j], acc2[i][j], 0, 0, 0);
        }
    }
    if (more) store_buf(cur ^ 1);
    __syncthreads();
  }

  // SwiGLU epilogue in f32, write h bf16 (list order)
  int rq = lane >> 4;
#pragma unroll
  for (int i = 0; i < 4; ++i)
#pragma unroll
    for (int r = 0; r < 4; ++r) {
      int mrow = wm + i * 16 + rq * 4 + r;
      int m = m0 + mrow;
      if (m < cnt) {
#pragma unroll
        for (int j = 0; j < 2; ++j) {
          int col = n0 + wn + j * 16 + rl;
          float g1 = acc1[i][j][r], g2 = acc2[i][j][r];
          float hv = g1 / (1.f + expf(-g1)) * g2;
          h[(size_t)(base + m) * NH + col] = f2bf(hv);
        }
      }
    }
}

// ---------------- GEMM3: out = h @ W3^T, scatter rows to token order ----------------
__global__ __launch_bounds__(256, 2) void moe_gemm3(
    const unsigned short* __restrict__ h, const float* __restrict__ W3f,
    const int* __restrict__ offsets, const int* __restrict__ token_list,
    float* __restrict__ out)
{
  int e = blockIdx.z;
  int base = offsets[e], cnt = offsets[e + 1] - base;
  int m0 = blockIdx.y * 128;
  if (m0 >= cnt) return;
  int n0 = blockIdx.x * 64;
  const float* B = W3f + (size_t)e * ((size_t)ND * NH) + (size_t)n0 * NH;

  __shared__ __align__(16) unsigned short As[2][128][LDK];
  __shared__ __align__(16) unsigned short Bs[2][64][LDK];
  __shared__ int rowtok[128];

  int t = threadIdx.x;
  if (t < 128) {
    int mc = m0 + t; if (mc > cnt - 1) mc = cnt - 1;
    rowtok[t] = token_list[base + mc];
  }
  __syncthreads();

  // A: h bf16, list-contiguous rows
  int rsub8 = t >> 3;           // 0..31
  int c8 = (t & 7) * 8;         // bf16 col
  const unsigned short* asrc[4];
#pragma unroll
  for (int rr = 0; rr < 4; ++rr) {
    int row = rr * 32 + rsub8;
    int mc = m0 + row; if (mc > cnt - 1) mc = cnt - 1;
    asrc[rr] = h + (size_t)(base + mc) * NH + c8;
  }
  int rsub = t >> 4;
  int c4 = (t & 15) * 4;
  const float* bsrc = B + (size_t)rsub * NH + c4;

  u32x4 ra[4];
  f32x4 rb[4];
  auto load_step = [&](int k0) {
#pragma unroll
    for (int rr = 0; rr < 4; ++rr) ra[rr] = *(const u32x4*)(asrc[rr] + k0);
#pragma unroll
    for (int rr = 0; rr < 4; ++rr) rb[rr] = *(const f32x4*)(bsrc + (size_t)rr * 16 * NH + k0);
  };
  auto store_buf = [&](int buf) {
#pragma unroll
    for (int rr = 0; rr < 4; ++rr) *(u32x4*)&As[buf][rr * 32 + rsub8][c8] = ra[rr];
#pragma unroll
    for (int rr = 0; rr < 4; ++rr) {
      u16x4 p;
      p[0] = f2bf(rb[rr][0]); p[1] = f2bf(rb[rr][1]);
      p[2] = f2bf(rb[rr][2]); p[3] = f2bf(rb[rr][3]);
      *(u16x4*)&Bs[buf][rr * 16 + rsub][c4] = p;
    }
  };

  int lane = t & 63, wid = t >> 6;
  int wm = (wid >> 1) * 64;
  int wn = (wid & 1) * 32;
  int rl = lane & 15;
  int ksel = (lane >> 4) * 8;

  f32x4 acc[4][2] = {};

  load_step(0);
  store_buf(0);
  __syncthreads();

  const int NSTEP = NH / 64;   // 56
  for (int ks = 0; ks < NSTEP; ++ks) {
    int cur = ks & 1;
    bool more = (ks + 1) < NSTEP;
    if (more) load_step((ks + 1) * 64);
#pragma unroll
    for (int kk = 0; kk < 2; ++kk) {
      int klo = kk * 32 + ksel;
      bf16x8 af[4], bv[2];
#pragma unroll
      for (int i = 0; i < 4; ++i) af[i] = *(const bf16x8*)&As[cur][wm + i * 16 + rl][klo];
#pragma unroll
      for (int j = 0; j < 2; ++j) bv[j] = *(const bf16x8*)&Bs[cur][wn + j * 16 + rl][klo];
#pragma unroll
      for (int i = 0; i < 4; ++i)
#pragma unroll
        for (int j = 0; j < 2; ++j)
          acc[i][j] = __builtin_amdgcn_mfma_f32_16x16x32_bf16(af[i], bv[j], acc[i][j], 0, 0, 0);
    }
    if (more) store_buf(cur ^ 1);
    __syncthreads();
  }

  int rq = lane >> 4;
#pragma unroll
  for (int i = 0; i < 4; ++i)
#pragma unroll
    for (int r = 0; r < 4; ++r) {
      int mrow = wm + i * 16 + rq * 4 + r;
      int m = m0 + mrow;
      if (m < cnt) {
        int tok = rowtok[mrow];
#pragma unroll
        for (int j = 0; j < 2; ++j) {
          int col = n0 + wn + j * 16 + rl;
          out[(size_t)tok * ND + col] = acc[i][j][r];
        }
      }
    }
}

extern "C" void kernel_launch(void* const* d_in, const int* in_sizes, int n_in,
                              void* d_out, int out_size, void* d_ws, size_t ws_size,
                              hipStream_t stream)
{
  (void)in_sizes; (void)n_in; (void)out_size; (void)ws_size;
  const float* x  = (const float*)d_in[0];
  const float* Wr = (const float*)d_in[1];
  const float* W1 = (const float*)d_in[2];
  const float* W2 = (const float*)d_in[3];
  const float* W3 = (const float*)d_in[4];
  float* out = (float*)d_out;

  char* w = (char*)d_ws;
  float* probs    = (float*)(w + 0);        // 65536 B
  float* lse      = (float*)(w + 65536);    // 8192 B
  int* counts     = (int*)(w + 73728);      // 32 B
  int* cursors    = (int*)(w + 73760);      // 32 B
  int* offsets    = (int*)(w + 73792);      // 64 B
  int* expert_of  = (int*)(w + 73856);      // 8192 B
  int* token_list = (int*)(w + 82048);      // 8192 B
  unsigned short* h = (unsigned short*)(w + 131072);   // NTOK*NH*2 = 14680064 B

  hipMemsetAsync(counts, 0, 32, stream);
  router_kernel<<<NTOK, 256, 0, stream>>>(x, Wr, probs, lse, counts, expert_of);
  aux_offsets_kernel<<<1, 256, 0, stream>>>(probs, lse, counts, offsets, cursors,
                                            out + (size_t)NTOK * ND);
  scatter_kernel<<<NTOK / 256, 256, 0, stream>>>(expert_of, cursors, token_list);
  moe_gemm12<<<dim3(NH / 64, NTOK / 128, NE), 256, 0, stream>>>(
      x, W1, W2, offsets, token_list, h);
  moe_gemm3<<<dim3(ND / 64, NTOK / 128, NE), 256, 0, stream>>>(
      h, W3, offsets, token_list, out);
}